// Round 10
// baseline (747.700 us; speedup 1.0000x reference)
//
#include <hip/hip_runtime.h>
#include <hip/hip_bf16.h>
#include <math.h>

// Problem constants (reference: N=8192, H=2048, E=8, K=2, CF=1.25)
#define NTOK 8192
#define HDIM 2048
#define NEXP 8
#define TOPK 2
#define CAP  1280            // ceil(1.25 * 8192 / 8)
#define FF   4096            // 2*H
#define BK   64              // GEMM K-step (128-B LDS rows)
#define BM   320             // GEMM M-tile (CAP = 4 x 320 exactly)
#define BN   256             // GEMM N-tile

typedef float  f32x4  __attribute__((ext_vector_type(4)));
typedef __bf16 bf16x8 __attribute__((ext_vector_type(8)));

typedef __attribute__((address_space(1))) const unsigned int gas_u32;
typedef __attribute__((address_space(3))) unsigned int las_u32;

__device__ __forceinline__ void gload16(const void* g, void* l) {
    // async global -> LDS, 16 B per lane; LDS dest = wave-uniform base + lane*16
    __builtin_amdgcn_global_load_lds((gas_u32*)g, (las_u32*)l, 16, 0, 0);
}

__device__ __forceinline__ ushort f2bf(float f) {
    union { float f; unsigned u; } c; c.f = f;
    unsigned u = c.u;
    unsigned r = (u + 0x7FFFu + ((u >> 16) & 1u)) >> 16;   // RNE
    return (ushort)r;
}
__device__ __forceinline__ float bf2f(ushort h) {
    union { unsigned u; float f; } c; c.u = ((unsigned)h) << 16;
    return c.f;
}

// ---------------- tokens f32 -> bf16 ----------------
__global__ void k_convert(const float* __restrict__ src, ushort* __restrict__ dst) {
    int i = (blockIdx.x * 256 + threadIdx.x) * 8;
    float4 a = *(const float4*)(src + i);
    float4 b = *(const float4*)(src + i + 4);
    uint4 o;
    o.x = (unsigned)f2bf(a.x) | ((unsigned)f2bf(a.y) << 16);
    o.y = (unsigned)f2bf(a.z) | ((unsigned)f2bf(a.w) << 16);
    o.z = (unsigned)f2bf(b.x) | ((unsigned)f2bf(b.y) << 16);
    o.w = (unsigned)f2bf(b.z) | ((unsigned)f2bf(b.w) << 16);
    *(uint4*)(dst + i) = o;
}

// ---------------- router: logits (f64 accum), top-2, softmax ----------------
__global__ void k_router(const float* __restrict__ tokens, const float* __restrict__ Wr,
                         const float* __restrict__ br, int* __restrict__ eids,
                         float* __restrict__ probs) {
    int wave = threadIdx.x >> 6, lane = threadIdx.x & 63;
    int t = blockIdx.x * 4 + wave;
    const float* tp = tokens + (size_t)t * HDIM;
    double acc[NEXP];
    #pragma unroll
    for (int e = 0; e < NEXP; ++e) acc[e] = 0.0;
    for (int j = 0; j < HDIM / 64; ++j) {
        float x = tp[j * 64 + lane];
        #pragma unroll
        for (int e = 0; e < NEXP; ++e)
            acc[e] += (double)x * (double)Wr[e * HDIM + j * 64 + lane];
    }
    #pragma unroll
    for (int e = 0; e < NEXP; ++e) {
        #pragma unroll
        for (int off = 32; off; off >>= 1) acc[e] += __shfl_xor(acc[e], off, 64);
    }
    if (lane == 0) {
        float lg[NEXP];
        #pragma unroll
        for (int e = 0; e < NEXP; ++e) lg[e] = (float)acc[e] + br[e];
        int e0 = 0; float s0 = lg[0];
        #pragma unroll
        for (int e = 1; e < NEXP; ++e) if (lg[e] > s0) { s0 = lg[e]; e0 = e; }
        int e1 = -1; float s1 = -1e30f;
        #pragma unroll
        for (int e = 0; e < NEXP; ++e) if (e != e0 && lg[e] > s1) { s1 = lg[e]; e1 = e; }
        float ex = expf(s1 - s0);
        float den = 1.f + ex;
        eids[t * 2] = e0; eids[t * 2 + 1] = e1;
        probs[t * 2] = 1.f / den; probs[t * 2 + 1] = ex / den;
    }
}

// ---------------- deterministic rank/capacity assignment (1 block, 1 wave) ----------------
__global__ void k_assign(const int* __restrict__ eids, int* __restrict__ tok_map,
                         int* __restrict__ dest) {
    __shared__ int cnt[64][NEXP];
    int l = threadIdx.x;
    for (int i = l; i < NEXP * CAP; i += 64) tok_map[i] = 0;
    int c[NEXP];
    #pragma unroll
    for (int e = 0; e < NEXP; ++e) c[e] = 0;
    const int base = l * 256;
    for (int i = 0; i < 256; ++i) {
        int ee = eids[base + i];
        #pragma unroll
        for (int e = 0; e < NEXP; ++e) c[e] += (ee == e);
    }
    #pragma unroll
    for (int e = 0; e < NEXP; ++e) cnt[l][e] = c[e];
    __syncthreads();
    if (l < NEXP) {
        int run = 0;
        for (int b = 0; b < 64; ++b) { int v = cnt[b][l]; cnt[b][l] = run; run += v; }
    }
    __syncthreads();
    int off[NEXP];
    #pragma unroll
    for (int e = 0; e < NEXP; ++e) off[e] = cnt[l][e];
    for (int i = 0; i < 256; ++i) {
        int d = base + i;
        int ee = eids[d];
        int r = -1;
        #pragma unroll
        for (int e = 0; e < NEXP; ++e) { bool m = (ee == e); if (m) r = off[e]; off[e] += m; }
        if (r < CAP) { tok_map[ee * CAP + r] = d >> 1; dest[d] = ee * CAP + r; }
        else dest[d] = -1;
    }
}

// ---------------- W [E][Kd][Nd] f32 -> WT [E][Nd][Kd] bf16, 64x64 tiles ----------------
__global__ __launch_bounds__(256) void k_transpose(const float* __restrict__ src,
                                                   ushort* __restrict__ dst,
                                                   int Kd, int Nd) {
    __shared__ float tl[64][65];
    int e = blockIdx.z;
    int k0 = blockIdx.x * 64, n0 = blockIdx.y * 64;
    const float* s = src + (size_t)e * Kd * Nd;
    ushort* d = dst + (size_t)e * Kd * Nd;
    int tid = threadIdx.x;
    #pragma unroll
    for (int i = 0; i < 4; ++i) {
        int flat = (i * 256 + tid) * 4;
        int kk = flat >> 6, nn = flat & 63;
        float4 v = *(const float4*)(s + (size_t)(k0 + kk) * Nd + n0 + nn);
        tl[kk][nn] = v.x; tl[kk][nn + 1] = v.y; tl[kk][nn + 2] = v.z; tl[kk][nn + 3] = v.w;
    }
    __syncthreads();
    #pragma unroll
    for (int g = 0; g < 4; ++g) {
        int flat = g * 1024 + tid * 4;
        int nn = flat >> 6, kk = flat & 63;
        uint2 o;
        o.x = (unsigned)f2bf(tl[kk][nn])     | ((unsigned)f2bf(tl[kk + 1][nn]) << 16);
        o.y = (unsigned)f2bf(tl[kk + 2][nn]) | ((unsigned)f2bf(tl[kk + 3][nn]) << 16);
        *(uint2*)(d + (size_t)(n0 + nn) * Kd + k0 + kk) = o;
    }
}

// ---------------- grouped bf16 MFMA GEMM: 320x256, BK=64, 8 waves (4x2), 2-buffer ----------------
// C = act(A . B^T + bias). A: rows of Kd bf16 (via tmap if GATHER, else slot rows).
// B: [E][Nd][Kd] bf16 (K-contiguous). C: [E][CAP][Nd] bf16.
// Rationale (round-9 finding: kernel is LDS-BW-bound at ~85-90 B/cyc/CU):
//   traffic/FLOP = (M_w+N_w)/(M_w*N_w); 64x64 wave-tile = 0.031 B/F, 80x128 = 0.020 B/F.
//   Per iter: reads A40K*2 + B32K*4 = 208 KB + writes 72 KB = 280 KB = ~3294 cyc; MFMA
//   ~3111 cyc -> balanced. Grid: GEMM2 = 256 blocks = exactly 1/CU; GEMM1 = 512 = 2 rounds.
// Pipeline (proven round 9): STAGE(t+1 -> other buf); ds_reads+MFMA(t); vmcnt(0); barrier.
// LDS 144 KiB: per buf A [320 rows][128 B] @0, B [256 rows][128 B] @40960; buf stride 73728.
// Swizzle (verified conflict-free, round 9): stage pos=tid&7 holds chunk pos^(row&7)
// (row = q*64 + (tid>>3), 64|q*64 so XOR term is (tid>>3)&7, round-invariant);
// read chunk c=ks*4+kq at position c^(row&7). Wave bases 80/128 are 0 mod 8.
#define SCHED0() __builtin_amdgcn_sched_barrier(0)
#define VMC0()   do { asm volatile("s_waitcnt vmcnt(0)" ::: "memory"); } while (0)

template<bool DOGELU, bool GATHER>
__global__ __launch_bounds__(512, 1) void k_gemm(const ushort* __restrict__ A,
                                                 const int* __restrict__ tmap,
                                                 const ushort* __restrict__ B,
                                                 const float* __restrict__ bias,
                                                 ushort* __restrict__ C,
                                                 int Kd, int Nd) {
    __shared__ __attribute__((aligned(128))) char lds[147456];  // 2 x (A 40K + B 32K)
    const int tid  = threadIdx.x;
    const int lane = tid & 63;
    const int wave = tid >> 6;                    // 0..7
    const int wr = wave >> 1, wc = wave & 1;      // 4x2 wave grid; per-wave 80 x 128
    const int e = blockIdx.z;
    const int bm0 = blockIdx.y * BM, bn0 = blockIdx.x * BN;

    const ushort* Be = B + (size_t)e * (size_t)Nd * Kd;
    // staging: round q stages rows q*64 + (tid>>3); thread's chunk pos = tid&7;
    // source k-chunk = (tid&7) ^ ((tid>>3)&7) (round-invariant: rows step by 64)
    const int rbase = tid >> 3;                   // 0..63
    const int kc = ((tid & 7) ^ (rbase & 7)) * 8;
    const ushort* pa[5]; const ushort* pb[4];
    #pragma unroll
    for (int q = 0; q < 5; ++q) {                 // A: 5 rounds x 64 rows = 320
        int gr = q * 64 + rbase;
        int arow = GATHER ? tmap[e * CAP + bm0 + gr] : (e * CAP + bm0 + gr);
        pa[q] = A + (size_t)arow * Kd + kc;
    }
    #pragma unroll
    for (int q = 0; q < 4; ++q)                   // B: 4 rounds x 64 rows = 256
        pb[q] = Be + (size_t)(bn0 + q * 64 + rbase) * Kd + kc;

    auto STAGE = [&](int buf, int kt) {
        char* d = lds + buf * 73728;
        #pragma unroll
        for (int q = 0; q < 5; ++q)
            gload16(pa[q] + kt * BK, d + q * 8192 + tid * 16);
        #pragma unroll
        for (int q = 0; q < 4; ++q)
            gload16(pb[q] + kt * BK, d + 40960 + q * 8192 + tid * 16);
    };

    // compute-side fragment addressing (swizzled read)
    const int fr = lane & 15, kq = lane >> 4;
    int offA[5][2], offB[8][2];
    #pragma unroll
    for (int m = 0; m < 5; ++m) {
        int row = wr * 80 + m * 16 + fr;
        #pragma unroll
        for (int ks = 0; ks < 2; ++ks)
            offA[m][ks] = row * 128 + (((ks * 4 + kq) ^ (row & 7)) * 16);
    }
    #pragma unroll
    for (int n = 0; n < 8; ++n) {
        int row = wc * 128 + n * 16 + fr;
        #pragma unroll
        for (int ks = 0; ks < 2; ++ks)
            offB[n][ks] = 40960 + row * 128 + (((ks * 4 + kq) ^ (row & 7)) * 16);
    }

    f32x4 acc[5][8] = {};
    const int nt = Kd / BK;

    STAGE(0, 0);
    VMC0();
    __builtin_amdgcn_s_barrier();
    for (int t = 0; t < nt; ++t) {
        if (t + 1 < nt) STAGE((t + 1) & 1, t + 1);
        SCHED0();
        const char* rb = lds + (t & 1) * 73728;
        bf16x8 af[5][2], bf[8][2];
        #pragma unroll
        for (int m = 0; m < 5; ++m)
            #pragma unroll
            for (int ks = 0; ks < 2; ++ks)
                af[m][ks] = *(const bf16x8*)(rb + offA[m][ks]);
        #pragma unroll
        for (int n = 0; n < 8; ++n)
            #pragma unroll
            for (int ks = 0; ks < 2; ++ks)
                bf[n][ks] = *(const bf16x8*)(rb + offB[n][ks]);
        #pragma unroll
        for (int ks = 0; ks < 2; ++ks)
            #pragma unroll
            for (int m = 0; m < 5; ++m)
                #pragma unroll
                for (int n = 0; n < 8; ++n)
                    acc[m][n] = __builtin_amdgcn_mfma_f32_16x16x32_bf16(af[m][ks], bf[n][ks],
                                                                        acc[m][n], 0, 0, 0);
        VMC0();                                    // tile t+1 landed (issued a full phase ago)
        __builtin_amdgcn_s_barrier();              // publish buf[(t+1)&1]; reads of t done
    }

    const float* be = bias + e * Nd;
    ushort* Ce = C + (size_t)e * CAP * Nd;
    const int rl = (lane >> 4) * 4, cl = lane & 15;
    #pragma unroll
    for (int ni = 0; ni < 8; ++ni) {
        int gc = bn0 + wc * 128 + ni * 16 + cl;
        float bv = be[gc];
        #pragma unroll
        for (int mi = 0; mi < 5; ++mi) {
            #pragma unroll
            for (int r = 0; r < 4; ++r) {
                int gr = bm0 + wr * 80 + mi * 16 + rl + r;
                float v = acc[mi][ni][r] + bv;
                if (DOGELU) v = 0.5f * v * (1.f + erff(v * 0.70710678118654752f));
                Ce[(size_t)gr * Nd + gc] = f2bf(v);
            }
        }
    }
}

// ---------------- deterministic combine: out[t] = sum_k p_k * Y[dest_k] ----------------
__global__ void k_combine(const ushort* __restrict__ Y, const int* __restrict__ dest,
                          const float* __restrict__ probs, float* __restrict__ out) {
    int t = blockIdx.x;
    int h0 = threadIdx.x * 8;
    int d0 = dest[t * 2], d1 = dest[t * 2 + 1];
    float p0 = d0 >= 0 ? probs[t * 2] : 0.f;
    float p1 = d1 >= 0 ? probs[t * 2 + 1] : 0.f;
    int r0 = d0 >= 0 ? d0 : 0, r1 = d1 >= 0 ? d1 : 0;
    uint4 a = *(const uint4*)(Y + (size_t)r0 * HDIM + h0);
    uint4 b = *(const uint4*)(Y + (size_t)r1 * HDIM + h0);
    float4 o0, o1;
    o0.x = p0 * bf2f(a.x & 0xffff) + p1 * bf2f(b.x & 0xffff);
    o0.y = p0 * bf2f(a.x >> 16)    + p1 * bf2f(b.x >> 16);
    o0.z = p0 * bf2f(a.y & 0xffff) + p1 * bf2f(b.y & 0xffff);
    o0.w = p0 * bf2f(a.y >> 16)    + p1 * bf2f(b.y >> 16);
    o1.x = p0 * bf2f(a.z & 0xffff) + p1 * bf2f(b.z & 0xffff);
    o1.y = p0 * bf2f(a.z >> 16)    + p1 * bf2f(b.z >> 16);
    o1.z = p0 * bf2f(a.w & 0xffff) + p1 * bf2f(b.w & 0xffff);
    o1.w = p0 * bf2f(a.w >> 16)    + p1 * bf2f(b.w >> 16);
    float* op = out + (size_t)t * HDIM + h0;
    *(float4*)op = o0;
    *(float4*)(op + 4) = o1;
}

extern "C" void kernel_launch(void* const* d_in, const int* in_sizes, int n_in,
                              void* d_out, int out_size, void* d_ws, size_t ws_size,
                              hipStream_t stream) {
    const float* tokens = (const float*)d_in[0];
    const float* Wr     = (const float*)d_in[1];
    const float* br     = (const float*)d_in[2];
    const float* W1     = (const float*)d_in[3];
    const float* b1     = (const float*)d_in[4];
    const float* W2     = (const float*)d_in[5];
    const float* b2     = (const float*)d_in[6];
    float* out = (float*)d_out;
    char* ws = (char*)d_ws;

    int*    eids    = (int*)(ws);
    float*  probs   = (float*)(ws + 65536);
    int*    tok_map = (int*)(ws + 131072);
    int*    dest    = (int*)(ws + 172032);
    size_t off = 1u << 20;
    ushort* TbY = (ushort*)(ws + off);             // tokens bf16 (33.5 MB) then Y bf16 (41.9 MB)
    off += 41943040;
    ushort* Hm  = (ushort*)(ws + off);             // gelu hidden bf16, 83.9 MB
    off += 83886080;
    ushort* WT  = (ushort*)(ws + off);             // W1T then W2T bf16, 134.2 MB
    (void)in_sizes; (void)n_in; (void)out_size; (void)ws_size;

    k_convert<<<dim3(NTOK * HDIM / 2048), 256, 0, stream>>>(tokens, TbY);
    k_router<<<dim3(NTOK / 4), 256, 0, stream>>>(tokens, Wr, br, eids, probs);
    k_assign<<<dim3(1), 64, 0, stream>>>(eids, tok_map, dest);
    k_transpose<<<dim3(HDIM / 64, FF / 64, NEXP), 256, 0, stream>>>(W1, WT, HDIM, FF);
    k_gemm<true, true><<<dim3(FF / BN, CAP / BM, NEXP), 512, 0, stream>>>(
        TbY, tok_map, WT, b1, Hm, HDIM, FF);
    k_transpose<<<dim3(FF / 64, HDIM / 64, NEXP), 256, 0, stream>>>(W2, WT, FF, HDIM);
    k_gemm<false, false><<<dim3(HDIM / BN, CAP / BM, NEXP), 512, 0, stream>>>(
        Hm, nullptr, WT, b2, TbY, FF, HDIM);
    k_combine<<<dim3(NTOK), 256, 0, stream>>>(TbY, dest, probs, out);
}